// Round 3
// baseline (759.843 us; speedup 1.0000x reference)
//
#include <hip/hip_runtime.h>

#define TPB 256
#define NBLK_EDGE 512          // blocks for hist/reorder; chunking must match between them
#define BIN_SHIFT 10
#define BIN_SIZE 1024          // nodes per bin
#define MAXK 512               // max bins (N=500K -> K=489)
#define ROW_BITS 19            // N=500,000 < 2^19
#define ROW_MASK ((1u << ROW_BITS) - 1)

typedef _Float16 half8  __attribute__((ext_vector_type(8)));
typedef _Float16 half2v __attribute__((ext_vector_type(2)));

__global__ void k_zero_int(int* __restrict__ p, int n) {
    int i = blockIdx.x * blockDim.x + threadIdx.x;
    if (i < n) p[i] = 0;
}

// Per-block LDS histogram of col>>BIN_SHIFT, merged with K atomics per block.
__global__ void k_hist(const int* __restrict__ col, int E, int chunk, int K,
                       int* __restrict__ ghist) {
    __shared__ int lh[MAXK];
    for (int k = threadIdx.x; k < K; k += blockDim.x) lh[k] = 0;
    __syncthreads();
    int s = blockIdx.x * chunk, e_ = min(s + chunk, E);
    for (int e = s + threadIdx.x; e < e_; e += blockDim.x)
        atomicAdd(&lh[col[e] >> BIN_SHIFT], 1);
    __syncthreads();
    for (int k = threadIdx.x; k < K; k += blockDim.x)
        if (lh[k]) atomicAdd(&ghist[k], lh[k]);
}

// Parallel exclusive scan over K<=MAXK bins (single block of MAXK threads).
__global__ void k_scan(const int* __restrict__ ghist, int K,
                       int* __restrict__ binBase, int* __restrict__ cursor) {
    __shared__ int tmp[MAXK];
    int tid = threadIdx.x;
    int val = (tid < K) ? ghist[tid] : 0;
    tmp[tid] = val;
    __syncthreads();
    for (int off = 1; off < MAXK; off <<= 1) {
        int v = (tid >= off) ? tmp[tid - off] : 0;
        __syncthreads();
        tmp[tid] += v;
        __syncthreads();
    }
    int incl = tmp[tid];
    int excl = incl - val;
    if (tid < K) { binBase[tid] = excl; cursor[tid] = excl; }
    if (tid == K - 1) binBase[K] = incl;  // == E
}

// Counting-sort reorder: per-block LDS hist -> block-level reservation in global
// cursor -> scatter packed edges (local_col<<19 | row) into bin-contiguous storage.
__global__ void k_reorder(const int* __restrict__ row, const int* __restrict__ col,
                          int E, int chunk, int K,
                          int* __restrict__ cursor, unsigned* __restrict__ packed) {
    __shared__ int lh[MAXK];
    for (int k = threadIdx.x; k < K; k += blockDim.x) lh[k] = 0;
    __syncthreads();
    int s = blockIdx.x * chunk, e_ = min(s + chunk, E);
    for (int e = s + threadIdx.x; e < e_; e += blockDim.x)
        atomicAdd(&lh[col[e] >> BIN_SHIFT], 1);
    __syncthreads();
    for (int k = threadIdx.x; k < K; k += blockDim.x) {
        int c = lh[k];
        lh[k] = c ? atomicAdd(&cursor[k], c) : 0;  // lh becomes running write cursor
    }
    __syncthreads();
    for (int e = s + threadIdx.x; e < e_; e += blockDim.x) {
        int c = col[e];
        int b = c >> BIN_SHIFT;
        unsigned lc = (unsigned)(c & (BIN_SIZE - 1));
        int pos = atomicAdd(&lh[b], 1);            // LDS atomic, returns slot
        packed[pos] = (lc << ROW_BITS) | (unsigned)row[e];
    }
}

// Fused per-bin: degree count (LDS) -> dinv = rsqrt(deg+1) -> g0 = f16(dinv*(x@W1))
__global__ void k_deg_node1(const unsigned* __restrict__ packed, const int* __restrict__ binBase,
                            const float* __restrict__ x, const float* __restrict__ W1,
                            float* __restrict__ dinv, half8* __restrict__ g0, int N) {
    __shared__ int cnt[BIN_SIZE];
    for (int i = threadIdx.x; i < BIN_SIZE; i += blockDim.x) cnt[i] = 0;
    __syncthreads();
    int bin = blockIdx.x;
    int s = binBase[bin], t = binBase[bin + 1];
    for (int e = s + (int)threadIdx.x; e < t; e += blockDim.x)
        atomicAdd(&cnt[packed[e] >> ROW_BITS], 1);
    __syncthreads();
    int base = bin << BIN_SHIFT;
    int lim = min(BIN_SIZE, N - base);
    for (int n = threadIdx.x; n < lim; n += blockDim.x) {
        int i = base + n;
        float di = rsqrtf((float)(cnt[n] + 1));  // +1 self-loop
        dinv[i] = di;
        const float4* xv = (const float4*)(x + (size_t)i * 16);
        float4 a0 = xv[0], a1 = xv[1], a2 = xv[2], a3 = xv[3];
        float xl[16] = {a0.x, a0.y, a0.z, a0.w, a1.x, a1.y, a1.z, a1.w,
                        a2.x, a2.y, a2.z, a2.w, a3.x, a3.y, a3.z, a3.w};
        float h[8];
#pragma unroll
        for (int j = 0; j < 8; ++j) h[j] = 0.0f;
#pragma unroll
        for (int k = 0; k < 16; ++k) {
            float xk = xl[k];
#pragma unroll
            for (int j = 0; j < 8; ++j) h[j] += xk * W1[k * 8 + j];
        }
        half8 g;
#pragma unroll
        for (int j = 0; j < 8; ++j) g[j] = (_Float16)(di * h[j]);
        g0[i] = g;
    }
}

// Binned LDS scatter, 8 channels, f16 gather (ONE 16B request per edge).
// 2x-unrolled edge loop for MLP. Writeback folds in self-loop (acc1 = tile + g0).
__global__ void __launch_bounds__(512) k_scatter1(
        const unsigned* __restrict__ packed, const int* __restrict__ binBase,
        const half8* __restrict__ g0, float* __restrict__ acc1, int N) {
    __shared__ float tile[8 * BIN_SIZE];  // 32 KB
    for (int i = threadIdx.x; i < 8 * BIN_SIZE; i += blockDim.x) tile[i] = 0.0f;
    __syncthreads();
    int bin = blockIdx.x;
    int s = binBase[bin], t = binBase[bin + 1];
    const int stride = blockDim.x;
    int e = s + (int)threadIdx.x;
    for (; e + stride < t; e += 2 * stride) {
        unsigned p0 = packed[e], p1 = packed[e + stride];
        half8 v0 = g0[p0 & ROW_MASK];
        half8 v1 = g0[p1 & ROW_MASK];
        int lc0 = (int)(p0 >> ROW_BITS), lc1 = (int)(p1 >> ROW_BITS);
#pragma unroll
        for (int ch = 0; ch < 8; ++ch)
            atomicAdd(&tile[ch * BIN_SIZE + lc0], (float)v0[ch]);
#pragma unroll
        for (int ch = 0; ch < 8; ++ch)
            atomicAdd(&tile[ch * BIN_SIZE + lc1], (float)v1[ch]);
    }
    if (e < t) {
        unsigned p = packed[e];
        half8 v = g0[p & ROW_MASK];
        int lc = (int)(p >> ROW_BITS);
#pragma unroll
        for (int ch = 0; ch < 8; ++ch)
            atomicAdd(&tile[ch * BIN_SIZE + lc], (float)v[ch]);
    }
    __syncthreads();
    int base = bin << BIN_SHIFT;
    int lim = min(BIN_SIZE, N - base);
    for (int n = threadIdx.x; n < lim; n += blockDim.x) {
        half8 sv = g0[base + n];
        float4* av = (float4*)(acc1 + (size_t)(base + n) * 8);
        av[0] = make_float4(tile[0 * BIN_SIZE + n] + (float)sv[0],
                            tile[1 * BIN_SIZE + n] + (float)sv[1],
                            tile[2 * BIN_SIZE + n] + (float)sv[2],
                            tile[3 * BIN_SIZE + n] + (float)sv[3]);
        av[1] = make_float4(tile[4 * BIN_SIZE + n] + (float)sv[4],
                            tile[5 * BIN_SIZE + n] + (float)sv[5],
                            tile[6 * BIN_SIZE + n] + (float)sv[6],
                            tile[7 * BIN_SIZE + n] + (float)sv[7]);
    }
}

// h = relu(dinv*acc1 + b1); g1 = f16(dinv*(h @ W2))
__global__ void k_node2(const float* __restrict__ dinv_arr, const float* __restrict__ acc1,
                        const float* __restrict__ b1, const float* __restrict__ W2,
                        half2v* __restrict__ g1, int N) {
    int i = blockIdx.x * blockDim.x + threadIdx.x;
    if (i >= N) return;
    float dinv = dinv_arr[i];
    const float4* av = (const float4*)(acc1 + (size_t)i * 8);
    float4 lo = av[0], hi = av[1];
    float h[8] = {lo.x, lo.y, lo.z, lo.w, hi.x, hi.y, hi.z, hi.w};
    float o0 = 0.0f, o1 = 0.0f;
#pragma unroll
    for (int j = 0; j < 8; ++j) {
        float hj = fmaxf(dinv * h[j] + b1[j], 0.0f);
        o0 += hj * W2[j * 2 + 0];
        o1 += hj * W2[j * 2 + 1];
    }
    half2v g;
    g.x = (_Float16)(dinv * o0);
    g.y = (_Float16)(dinv * o1);
    g1[i] = g;
}

// Binned LDS scatter (2ch, 4B f16x2 gather, g1 working set 2MB -> L2-resident)
// fused with the epilogue: out = log_softmax(dinv*(tile+g1_self) + b2).
__global__ void __launch_bounds__(512) k_scatter2_final(
        const unsigned* __restrict__ packed, const int* __restrict__ binBase,
        const half2v* __restrict__ g1, const float* __restrict__ dinv_arr,
        const float* __restrict__ b2, float* __restrict__ out, int N) {
    __shared__ float tile[2 * BIN_SIZE];  // 8 KB
    for (int i = threadIdx.x; i < 2 * BIN_SIZE; i += blockDim.x) tile[i] = 0.0f;
    __syncthreads();
    int bin = blockIdx.x;
    int s = binBase[bin], t = binBase[bin + 1];
    const int stride = blockDim.x;
    int e = s + (int)threadIdx.x;
    for (; e + stride < t; e += 2 * stride) {
        unsigned p0 = packed[e], p1 = packed[e + stride];
        half2v v0 = g1[p0 & ROW_MASK];
        half2v v1 = g1[p1 & ROW_MASK];
        int lc0 = (int)(p0 >> ROW_BITS), lc1 = (int)(p1 >> ROW_BITS);
        atomicAdd(&tile[lc0], (float)v0.x);
        atomicAdd(&tile[BIN_SIZE + lc0], (float)v0.y);
        atomicAdd(&tile[lc1], (float)v1.x);
        atomicAdd(&tile[BIN_SIZE + lc1], (float)v1.y);
    }
    if (e < t) {
        unsigned p = packed[e];
        half2v v = g1[p & ROW_MASK];
        int lc = (int)(p >> ROW_BITS);
        atomicAdd(&tile[lc], (float)v.x);
        atomicAdd(&tile[BIN_SIZE + lc], (float)v.y);
    }
    __syncthreads();
    float bb0 = b2[0], bb1 = b2[1];
    int base = bin << BIN_SHIFT;
    int lim = min(BIN_SIZE, N - base);
    for (int n = threadIdx.x; n < lim; n += blockDim.x) {
        int i = base + n;
        float di = dinv_arr[i];
        half2v sg = g1[i];
        float o0 = di * (tile[n] + (float)sg.x) + bb0;
        float o1 = di * (tile[BIN_SIZE + n] + (float)sg.y) + bb1;
        float m = fmaxf(o0, o1);
        float lse = m + logf(expf(o0 - m) + expf(o1 - m));
        ((float2*)out)[i] = make_float2(o0 - lse, o1 - lse);
    }
}

extern "C" void kernel_launch(void* const* d_in, const int* in_sizes, int n_in,
                              void* d_out, int out_size, void* d_ws, size_t ws_size,
                              hipStream_t stream) {
    const float* x  = (const float*)d_in[0];
    const float* W1 = (const float*)d_in[1];
    const float* b1 = (const float*)d_in[2];
    const float* W2 = (const float*)d_in[3];
    const float* b2 = (const float*)d_in[4];
    const int*   ei = (const int*)d_in[5];

    const int N = in_sizes[0] / 16;
    const int E = in_sizes[5] / 2;
    const int* row = ei;
    const int* col = ei + E;
    const int K = (N + BIN_SIZE - 1) >> BIN_SHIFT;  // 489 for N=500K

    float* ws   = (float*)d_ws;
    float* dinv = ws;                        // N floats
    float* acc1 = ws + (size_t)N;            // 8N floats
    half8* g0   = (half8*)(ws + (size_t)9  * N);  // 4N floats worth (f16x8 per node)
    half2v* g1  = (half2v*)(ws + (size_t)13 * N); // N floats worth (f16x2 per node)
    int*   meta = (int*)(ws + (size_t)14 * N);
    int* ghist   = meta;                     // K ints
    int* binBase = meta + MAXK;              // K+1 ints
    int* cursor  = meta + 2 * MAXK + 8;      // K ints
    unsigned* packed = (unsigned*)(meta + 4 * MAXK);  // E uints

    float* out = (float*)d_out;

    const int gN = (N + TPB - 1) / TPB;
    const int chunk = (E + NBLK_EDGE - 1) / NBLK_EDGE;

    k_zero_int   <<<1, MAXK, 0, stream>>>(ghist, K);
    k_hist       <<<NBLK_EDGE, TPB, 0, stream>>>(col, E, chunk, K, ghist);
    k_scan       <<<1, MAXK, 0, stream>>>(ghist, K, binBase, cursor);
    k_reorder    <<<NBLK_EDGE, TPB, 0, stream>>>(row, col, E, chunk, K, cursor, packed);
    k_deg_node1  <<<K, TPB, 0, stream>>>(packed, binBase, x, W1, dinv, g0, N);
    k_scatter1   <<<K, 512, 0, stream>>>(packed, binBase, g0, acc1, N);
    k_node2      <<<gN, TPB, 0, stream>>>(dinv, acc1, b1, W2, g1, N);
    k_scatter2_final<<<K, 512, 0, stream>>>(packed, binBase, g1, dinv, b2, out, N);
}

// Round 4
// 757.939 us; speedup vs baseline: 1.0025x; 1.0025x over previous
//
#include <hip/hip_runtime.h>

#define TPB 256
#define NBLK_EDGE 512          // blocks for hist/reorder; chunking must match between them
#define BIN_SHIFT 10
#define BIN_SIZE 1024          // nodes per bin
#define MAXK 512               // max bins (N=500K -> K=489)
#define ROW_BITS 19            // N=500,000 < 2^19
#define ROW_MASK ((1u << ROW_BITS) - 1)
#define UNROLL 8               // outstanding gathers per thread in scatter kernels

typedef _Float16 half8  __attribute__((ext_vector_type(8)));
typedef _Float16 half2v __attribute__((ext_vector_type(2)));

__global__ void k_zero_int(int* __restrict__ p, int n) {
    int i = blockIdx.x * blockDim.x + threadIdx.x;
    if (i < n) p[i] = 0;
}

// Per-block LDS histogram of col>>BIN_SHIFT, merged with K atomics per block.
__global__ void k_hist(const int* __restrict__ col, int E, int chunk, int K,
                       int* __restrict__ ghist) {
    __shared__ int lh[MAXK];
    for (int k = threadIdx.x; k < K; k += blockDim.x) lh[k] = 0;
    __syncthreads();
    int s = blockIdx.x * chunk, e_ = min(s + chunk, E);
    for (int e = s + threadIdx.x; e < e_; e += blockDim.x)
        atomicAdd(&lh[col[e] >> BIN_SHIFT], 1);
    __syncthreads();
    for (int k = threadIdx.x; k < K; k += blockDim.x)
        if (lh[k]) atomicAdd(&ghist[k], lh[k]);
}

// Parallel exclusive scan over K<=MAXK bins (single block of MAXK threads).
__global__ void k_scan(const int* __restrict__ ghist, int K,
                       int* __restrict__ binBase, int* __restrict__ cursor) {
    __shared__ int tmp[MAXK];
    int tid = threadIdx.x;
    int val = (tid < K) ? ghist[tid] : 0;
    tmp[tid] = val;
    __syncthreads();
    for (int off = 1; off < MAXK; off <<= 1) {
        int v = (tid >= off) ? tmp[tid - off] : 0;
        __syncthreads();
        tmp[tid] += v;
        __syncthreads();
    }
    int incl = tmp[tid];
    int excl = incl - val;
    if (tid < K) { binBase[tid] = excl; cursor[tid] = excl; }
    if (tid == K - 1) binBase[K] = incl;  // == E
}

// Counting-sort reorder: per-block LDS hist -> block-level reservation in global
// cursor -> scatter packed edges (local_col<<19 | row) into bin-contiguous storage.
__global__ void k_reorder(const int* __restrict__ row, const int* __restrict__ col,
                          int E, int chunk, int K,
                          int* __restrict__ cursor, unsigned* __restrict__ packed) {
    __shared__ int lh[MAXK];
    for (int k = threadIdx.x; k < K; k += blockDim.x) lh[k] = 0;
    __syncthreads();
    int s = blockIdx.x * chunk, e_ = min(s + chunk, E);
    for (int e = s + threadIdx.x; e < e_; e += blockDim.x)
        atomicAdd(&lh[col[e] >> BIN_SHIFT], 1);
    __syncthreads();
    for (int k = threadIdx.x; k < K; k += blockDim.x) {
        int c = lh[k];
        lh[k] = c ? atomicAdd(&cursor[k], c) : 0;  // lh becomes running write cursor
    }
    __syncthreads();
    for (int e = s + threadIdx.x; e < e_; e += blockDim.x) {
        int c = col[e];
        int b = c >> BIN_SHIFT;
        unsigned lc = (unsigned)(c & (BIN_SIZE - 1));
        int pos = atomicAdd(&lh[b], 1);            // LDS atomic, returns slot
        packed[pos] = (lc << ROW_BITS) | (unsigned)row[e];
    }
}

// Fused per-bin: degree count (LDS) -> dinv = rsqrt(deg+1) -> g0 = f16(dinv*(x@W1))
__global__ void k_deg_node1(const unsigned* __restrict__ packed, const int* __restrict__ binBase,
                            const float* __restrict__ x, const float* __restrict__ W1,
                            float* __restrict__ dinv, half8* __restrict__ g0, int N) {
    __shared__ int cnt[BIN_SIZE];
    for (int i = threadIdx.x; i < BIN_SIZE; i += blockDim.x) cnt[i] = 0;
    __syncthreads();
    int bin = blockIdx.x;
    int s = binBase[bin], t = binBase[bin + 1];
    for (int e = s + (int)threadIdx.x; e < t; e += blockDim.x)
        atomicAdd(&cnt[packed[e] >> ROW_BITS], 1);
    __syncthreads();
    int base = bin << BIN_SHIFT;
    int lim = min(BIN_SIZE, N - base);
    for (int n = threadIdx.x; n < lim; n += blockDim.x) {
        int i = base + n;
        float di = rsqrtf((float)(cnt[n] + 1));  // +1 self-loop
        dinv[i] = di;
        const float4* xv = (const float4*)(x + (size_t)i * 16);
        float4 a0 = xv[0], a1 = xv[1], a2 = xv[2], a3 = xv[3];
        float xl[16] = {a0.x, a0.y, a0.z, a0.w, a1.x, a1.y, a1.z, a1.w,
                        a2.x, a2.y, a2.z, a2.w, a3.x, a3.y, a3.z, a3.w};
        float h[8];
#pragma unroll
        for (int j = 0; j < 8; ++j) h[j] = 0.0f;
#pragma unroll
        for (int k = 0; k < 16; ++k) {
            float xk = xl[k];
#pragma unroll
            for (int j = 0; j < 8; ++j) h[j] += xk * W1[k * 8 + j];
        }
        half8 g;
#pragma unroll
        for (int j = 0; j < 8; ++j) g[j] = (_Float16)(di * h[j]);
        g0[i] = g;
    }
}

// Binned LDS scatter, 8 channels, f16 gather. 8-deep software pipeline:
// issue UNROLL packed loads + UNROLL gathers before the dependent LDS atomics,
// so each wave keeps 8 random-line misses in flight (latency-bound regime).
__global__ void __launch_bounds__(512) k_scatter1(
        const unsigned* __restrict__ packed, const int* __restrict__ binBase,
        const half8* __restrict__ g0, float* __restrict__ acc1, int N) {
    __shared__ float tile[8 * BIN_SIZE];  // 32 KB
    for (int i = threadIdx.x; i < 8 * BIN_SIZE; i += blockDim.x) tile[i] = 0.0f;
    __syncthreads();
    int bin = blockIdx.x;
    int s = binBase[bin], t = binBase[bin + 1];
    const int stride = blockDim.x;
    int e = s + (int)threadIdx.x;
    for (; e + (UNROLL - 1) * stride < t; e += UNROLL * stride) {
        unsigned p[UNROLL];
#pragma unroll
        for (int u = 0; u < UNROLL; ++u) p[u] = packed[e + u * stride];
        half8 v[UNROLL];
#pragma unroll
        for (int u = 0; u < UNROLL; ++u) v[u] = g0[p[u] & ROW_MASK];
#pragma unroll
        for (int u = 0; u < UNROLL; ++u) {
            int lc = (int)(p[u] >> ROW_BITS);
#pragma unroll
            for (int ch = 0; ch < 8; ++ch)
                atomicAdd(&tile[ch * BIN_SIZE + lc], (float)v[u][ch]);
        }
    }
    for (; e < t; e += stride) {
        unsigned p = packed[e];
        half8 v = g0[p & ROW_MASK];
        int lc = (int)(p >> ROW_BITS);
#pragma unroll
        for (int ch = 0; ch < 8; ++ch)
            atomicAdd(&tile[ch * BIN_SIZE + lc], (float)v[ch]);
    }
    __syncthreads();
    int base = bin << BIN_SHIFT;
    int lim = min(BIN_SIZE, N - base);
    for (int n = threadIdx.x; n < lim; n += blockDim.x) {
        half8 sv = g0[base + n];
        float4* av = (float4*)(acc1 + (size_t)(base + n) * 8);
        av[0] = make_float4(tile[0 * BIN_SIZE + n] + (float)sv[0],
                            tile[1 * BIN_SIZE + n] + (float)sv[1],
                            tile[2 * BIN_SIZE + n] + (float)sv[2],
                            tile[3 * BIN_SIZE + n] + (float)sv[3]);
        av[1] = make_float4(tile[4 * BIN_SIZE + n] + (float)sv[4],
                            tile[5 * BIN_SIZE + n] + (float)sv[5],
                            tile[6 * BIN_SIZE + n] + (float)sv[6],
                            tile[7 * BIN_SIZE + n] + (float)sv[7]);
    }
}

// h = relu(dinv*acc1 + b1); g1 = f16(dinv*(h @ W2))
__global__ void k_node2(const float* __restrict__ dinv_arr, const float* __restrict__ acc1,
                        const float* __restrict__ b1, const float* __restrict__ W2,
                        half2v* __restrict__ g1, int N) {
    int i = blockIdx.x * blockDim.x + threadIdx.x;
    if (i >= N) return;
    float dinv = dinv_arr[i];
    const float4* av = (const float4*)(acc1 + (size_t)i * 8);
    float4 lo = av[0], hi = av[1];
    float h[8] = {lo.x, lo.y, lo.z, lo.w, hi.x, hi.y, hi.z, hi.w};
    float o0 = 0.0f, o1 = 0.0f;
#pragma unroll
    for (int j = 0; j < 8; ++j) {
        float hj = fmaxf(dinv * h[j] + b1[j], 0.0f);
        o0 += hj * W2[j * 2 + 0];
        o1 += hj * W2[j * 2 + 1];
    }
    half2v g;
    g.x = (_Float16)(dinv * o0);
    g.y = (_Float16)(dinv * o1);
    g1[i] = g;
}

// Binned LDS scatter (2ch, 4B f16x2 gather, g1 2MB -> mostly L2-resident),
// 8-deep pipelined, fused with log-softmax epilogue.
__global__ void __launch_bounds__(512) k_scatter2_final(
        const unsigned* __restrict__ packed, const int* __restrict__ binBase,
        const half2v* __restrict__ g1, const float* __restrict__ dinv_arr,
        const float* __restrict__ b2, float* __restrict__ out, int N) {
    __shared__ float tile[2 * BIN_SIZE];  // 8 KB
    for (int i = threadIdx.x; i < 2 * BIN_SIZE; i += blockDim.x) tile[i] = 0.0f;
    __syncthreads();
    int bin = blockIdx.x;
    int s = binBase[bin], t = binBase[bin + 1];
    const int stride = blockDim.x;
    int e = s + (int)threadIdx.x;
    for (; e + (UNROLL - 1) * stride < t; e += UNROLL * stride) {
        unsigned p[UNROLL];
#pragma unroll
        for (int u = 0; u < UNROLL; ++u) p[u] = packed[e + u * stride];
        half2v v[UNROLL];
#pragma unroll
        for (int u = 0; u < UNROLL; ++u) v[u] = g1[p[u] & ROW_MASK];
#pragma unroll
        for (int u = 0; u < UNROLL; ++u) {
            int lc = (int)(p[u] >> ROW_BITS);
            atomicAdd(&tile[lc], (float)v[u].x);
            atomicAdd(&tile[BIN_SIZE + lc], (float)v[u].y);
        }
    }
    for (; e < t; e += stride) {
        unsigned p = packed[e];
        half2v v = g1[p & ROW_MASK];
        int lc = (int)(p >> ROW_BITS);
        atomicAdd(&tile[lc], (float)v.x);
        atomicAdd(&tile[BIN_SIZE + lc], (float)v.y);
    }
    __syncthreads();
    float bb0 = b2[0], bb1 = b2[1];
    int base = bin << BIN_SHIFT;
    int lim = min(BIN_SIZE, N - base);
    for (int n = threadIdx.x; n < lim; n += blockDim.x) {
        int i = base + n;
        float di = dinv_arr[i];
        half2v sg = g1[i];
        float o0 = di * (tile[n] + (float)sg.x) + bb0;
        float o1 = di * (tile[BIN_SIZE + n] + (float)sg.y) + bb1;
        float m = fmaxf(o0, o1);
        float lse = m + logf(expf(o0 - m) + expf(o1 - m));
        ((float2*)out)[i] = make_float2(o0 - lse, o1 - lse);
    }
}

extern "C" void kernel_launch(void* const* d_in, const int* in_sizes, int n_in,
                              void* d_out, int out_size, void* d_ws, size_t ws_size,
                              hipStream_t stream) {
    const float* x  = (const float*)d_in[0];
    const float* W1 = (const float*)d_in[1];
    const float* b1 = (const float*)d_in[2];
    const float* W2 = (const float*)d_in[3];
    const float* b2 = (const float*)d_in[4];
    const int*   ei = (const int*)d_in[5];

    const int N = in_sizes[0] / 16;
    const int E = in_sizes[5] / 2;
    const int* row = ei;
    const int* col = ei + E;
    const int K = (N + BIN_SIZE - 1) >> BIN_SHIFT;  // 489 for N=500K

    float* ws   = (float*)d_ws;
    float* dinv = ws;                        // N floats
    float* acc1 = ws + (size_t)N;            // 8N floats
    half8* g0   = (half8*)(ws + (size_t)9  * N);  // 4N floats worth (f16x8 per node)
    half2v* g1  = (half2v*)(ws + (size_t)13 * N); // N floats worth (f16x2 per node)
    int*   meta = (int*)(ws + (size_t)14 * N);
    int* ghist   = meta;                     // K ints
    int* binBase = meta + MAXK;              // K+1 ints
    int* cursor  = meta + 2 * MAXK + 8;      // K ints
    unsigned* packed = (unsigned*)(meta + 4 * MAXK);  // E uints

    float* out = (float*)d_out;

    const int gN = (N + TPB - 1) / TPB;
    const int chunk = (E + NBLK_EDGE - 1) / NBLK_EDGE;

    k_zero_int   <<<1, MAXK, 0, stream>>>(ghist, K);
    k_hist       <<<NBLK_EDGE, TPB, 0, stream>>>(col, E, chunk, K, ghist);
    k_scan       <<<1, MAXK, 0, stream>>>(ghist, K, binBase, cursor);
    k_reorder    <<<NBLK_EDGE, TPB, 0, stream>>>(row, col, E, chunk, K, cursor, packed);
    k_deg_node1  <<<K, TPB, 0, stream>>>(packed, binBase, x, W1, dinv, g0, N);
    k_scatter1   <<<K, 512, 0, stream>>>(packed, binBase, g0, acc1, N);
    k_node2      <<<gN, TPB, 0, stream>>>(dinv, acc1, b1, W2, g1, N);
    k_scatter2_final<<<K, 512, 0, stream>>>(packed, binBase, g1, dinv, b2, out, N);
}